// Round 15
// baseline (2487.184 us; speedup 1.0000x reference)
//
#include <hip/hip_runtime.h>
#include <stdint.h>

typedef unsigned short u16;
typedef unsigned int   u32;

// problem dims
#define TB_ 8      // batch
#define NN_ 256    // state n
#define DD_ 684    // context depth d
#define PP_ 576    // H*W = 12*48

// workspace layout (bytes). Region0 [0, 1486848) time-shared BY LAUNCH ORDER:
//   phase1: UaCT (f32 [684][512]) @0        -- k_pre1 writes, k_pctx2 reads
//   phase2: sb @0 + buf @786432             -- k_pre2 writes AFTER k_pctx2 consumed UaCT
#define OFF_SB    0u
#define OFF_TRAN  0u
#define OFF_BUF   786432u
#define OFF_PCTX  1486848u    // f32 [b][p(576)][a(512)]
#define OFF_FKT   10924032u   // f32 [tap(9)][a(512)]
#define OFF_RAWP  10942464u   // f32 [b][ja(16)][p(576)]; row ja written by 2 blocks (p-halves)
#define OFF_H     11237376u   // f32 [b][n]
#define OFF_H0    11245568u   // f32 [b][n]
#define OFF_EAL   11253760u   // f32 [b][p] unnormalized e (owner-written, broadcast-read)
#define OFF_SYNC  11272192u   // u32 [b][128]: [0]=barrier ctr; f32 psums at [96..127]
#define OFF_FLG   11276288u   // int dtype flag
#define WS_NEED   11276304u

// output offsets (elements, f32)
#define OFF_H2   0
#define OFF_CTC  65536
#define OFF_CTP  240640
#define OFF_AL   415744
#define OFF_APO  563200

__device__ __forceinline__ float b2f(u16 v){ union{u32 i; float f;} x; x.i = ((u32)v)<<16; return x.f; }
__device__ __forceinline__ float gld(const void* p, size_t i, int f32){
  if (f32) return ((const float*)p)[i];
  return b2f(((const u16*)p)[i]);
}
__device__ __forceinline__ float bl(u32 v){ union{u32 i; float f;} x; x.i = v<<16; return x.f; }
__device__ __forceinline__ float bh(u32 v){ union{u32 i; float f;} x; x.i = v & 0xFFFF0000u; return x.f; }

// coherence-point (L3) scalar access for cross-block data.
__device__ __forceinline__ float aload(const float* p){
  u32 v = __hip_atomic_load((const u32*)p, __ATOMIC_RELAXED, __HIP_MEMORY_SCOPE_AGENT);
  union{u32 i; float f;} x; x.i = v; return x.f;
}
__device__ __forceinline__ void astore(float* p, float v){
  union{float f; u32 i;} x; x.f = v;
  __hip_atomic_store((u32*)p, x.i, __ATOMIC_RELAXED, __HIP_MEMORY_SCOPE_AGENT);
}

__device__ __forceinline__ float rcpf(float x){ return __builtin_amdgcn_rcpf(x); }
__device__ __forceinline__ float sigm(float x){
  x = fminf(fmaxf(x, -30.f), 30.f);
  return rcpf(1.f + __expf(-x));
}
__device__ __forceinline__ float tanh_c(float x){
  x = fminf(fmaxf(x, -15.f), 15.f);
  float e = __expf(2.f*x);
  return 1.f - 2.f*rcpf(e + 1.f);
}

__device__ __forceinline__ float dot8(uint4 u, const float* s){
  float a = fmaf(bl(u.x), s[0], bh(u.x)*s[1]);
  a = fmaf(bl(u.y), s[2], a); a = fmaf(bh(u.y), s[3], a);
  a = fmaf(bl(u.z), s[4], a); a = fmaf(bh(u.z), s[5], a);
  a = fmaf(bl(u.w), s[6], a); a = fmaf(bh(u.w), s[7], a);
  return a;
}
__device__ __forceinline__ float dot4t(uint2 u, const float* s, float a){
  a = fmaf(bl(u.x), s[0], a); a = fmaf(bh(u.x), s[1], a);
  a = fmaf(bl(u.y), s[2], a); a = fmaf(bh(u.y), s[3], a);
  return a;
}
__device__ __forceinline__ float dotf(const float* w, const float* s, int n){
  float a = 0.f;
  #pragma unroll 4
  for (int k=0;k<n;k+=4){
    float4 u = *(const float4*)(w+k);
    a = fmaf(u.x, s[k], a);   a = fmaf(u.y, s[k+1], a);
    a = fmaf(u.z, s[k+2], a); a = fmaf(u.w, s[k+3], a);
  }
  return a;
}
// n must be a multiple of 4
__device__ __forceinline__ float dotw(const void* W, size_t row_off, const float* s, int n, int f32){
  if (f32) return dotf((const float*)W + row_off, s, n);
  const u16* r = (const u16*)W + row_off;
  float a = 0.f;
  int k = 0;
  for (; k+8 <= n; k += 8) a += dot8(*(const uint4*)(r+k), s+k);
  if (k < n) a = dot4t(*(const uint2*)(r+k), s+k, a);
  return a;
}

// counter barrier (R1 primitive, zero outliers): __syncthreads drains all waves'
// vmem (compiler emits vmcnt(0) before s_barrier); tid0 RMW + throttled poll.
__device__ __forceinline__ void group_bar(u32* ctr, u32 target){
  __syncthreads();
  if (threadIdx.x == 0){
    __hip_atomic_fetch_add(ctr, 1u, __ATOMIC_RELAXED, __HIP_MEMORY_SCOPE_AGENT);
    while (__hip_atomic_load(ctr, __ATOMIC_RELAXED, __HIP_MEMORY_SCOPE_AGENT) < target)
      __builtin_amdgcn_s_sleep(2);
  }
  __syncthreads();
}

// ---------------- dtype detector ----------------
__global__ void k_detect(const u16* __restrict__ ctx_u16, int* __restrict__ flag){
  __shared__ int cnt;
  if (threadIdx.x == 0) cnt = 0;
  __syncthreads();
  int bad = 0;
  for (int k = threadIdx.x; k < 512; k += 256){
    u16 v = ctx_u16[k];
    int e = (v >> 7) & 0xFF;
    bool sane = (v == 0u) || (v == 0x8000u) || (e >= 102 && e <= 141);
    if (!sane) bad++;
  }
  atomicAdd(&cnt, bad);
  __syncthreads();
  if (threadIdx.x == 0) flag[0] = (cnt > 64) ? 1 : 0;
}

// ---------------- pre1: tran(88) + fk(32) = 120 blocks (runs BEFORE k_pctx2)
__global__ __launch_bounds__(256) void k_pre1(
    const void* __restrict__ UaC_w, float* __restrict__ UaCT,
    const void* __restrict__ QC, const void* __restrict__ UfC, float* __restrict__ FKt,
    const int* __restrict__ flag)
{
  const int f32 = flag[0];
  const int tid = threadIdx.x;
  __shared__ float smem[4608];
  int bid = blockIdx.x;

  if (bid < 88){
    int ab = bid / 11, db = bid - ab*11;
    int tc = tid & 63, tr = tid >> 6;
    int d0 = db*64, a0 = ab*64;
    for (int rr = tr; rr < 64; rr += 4){
      int d = d0 + tc;
      if (d < DD_) smem[rr*65 + tc] = gld(UaC_w, (size_t)(a0+rr)*DD_ + d, f32);
    }
    __syncthreads();
    for (int rr = tr; rr < 64; rr += 4){
      int d = d0 + rr;
      if (d < DD_) UaCT[(size_t)d*512 + a0 + tc] = smem[tc*65 + rr];
    }
    return;
  }
  bid -= 88;
  {
    for (int k=tid;k<4608;k+=256) smem[k] = gld(QC, k, f32);
    __syncthreads();
    const int lane = tid & 63;
    const int wid = bid*4 + (tid>>6);
    for (int rr=0; rr<4; rr++){
      const int a = wid*4 + rr;
      float acc[9];
      #pragma unroll
      for (int tt=0;tt<9;tt++) acc[tt]=0.f;
      #pragma unroll
      for (int k=0;k<8;k++){
        int c = lane + k*64;
        float v = gld(UfC, (size_t)a*512 + c, f32);
        const float* q = &smem[c*9];
        #pragma unroll
        for (int tt=0;tt<9;tt++) acc[tt] = fmaf(v, q[tt], acc[tt]);
      }
      #pragma unroll
      for (int off=1; off<64; off<<=1){
        #pragma unroll
        for (int tt=0;tt<9;tt++) acc[tt] += __shfl_xor(acc[tt], off, 64);
      }
      #pragma unroll
      for (int tt=0;tt<9;tt++) if (lane == tt) FKt[tt*512 + a] = acc[tt];
    }
  }
}

// pctx[b][p][a] = context[b,:,p].UaC[a,:] + UaC_b[a] + UfC_b[a]
__global__ __launch_bounds__(256) void k_pctx2(const void* __restrict__ context,
    const float* __restrict__ UaCT, const void* __restrict__ UaC_b, const void* __restrict__ UfC_b,
    float* __restrict__ pctx, const int* __restrict__ flag){
  const int f32 = flag[0];
  const int blk = blockIdx.x;
  const int b = blk / 18;
  const int pbase = (blk - b*18) * 32;
  __shared__ float ctx[32][DD_];
  const int tid = threadIdx.x;
  for (int k=tid; k<32*DD_; k+=256){
    int p = k & 31, d = k >> 5;
    ctx[p][d] = gld(context, ((size_t)(b*DD_+d))*PP_ + pbase + p, f32);
  }
  __syncthreads();
  const int a0 = (tid & 127) * 4;
  const int pr = (tid >> 7) * 16;
  float acc[16][4];
  #pragma unroll
  for (int p=0;p<16;p++){ acc[p][0]=0.f; acc[p][1]=0.f; acc[p][2]=0.f; acc[p][3]=0.f; }
  for (int d=0; d<DD_; d+=4){
    float4 w0 = *(const float4*)&UaCT[(size_t)(d+0)*512 + a0];
    float4 w1 = *(const float4*)&UaCT[(size_t)(d+1)*512 + a0];
    float4 w2 = *(const float4*)&UaCT[(size_t)(d+2)*512 + a0];
    float4 w3 = *(const float4*)&UaCT[(size_t)(d+3)*512 + a0];
    #pragma unroll
    for (int p=0;p<16;p++){
      float4 c = *(const float4*)(&ctx[pr+p][d]);
      acc[p][0] = fmaf(c.x, w0.x, acc[p][0]); acc[p][1] = fmaf(c.x, w0.y, acc[p][1]);
      acc[p][2] = fmaf(c.x, w0.z, acc[p][2]); acc[p][3] = fmaf(c.x, w0.w, acc[p][3]);
      acc[p][0] = fmaf(c.y, w1.x, acc[p][0]); acc[p][1] = fmaf(c.y, w1.y, acc[p][1]);
      acc[p][2] = fmaf(c.y, w1.z, acc[p][2]); acc[p][3] = fmaf(c.y, w1.w, acc[p][3]);
      acc[p][0] = fmaf(c.z, w2.x, acc[p][0]); acc[p][1] = fmaf(c.z, w2.y, acc[p][1]);
      acc[p][2] = fmaf(c.z, w2.z, acc[p][2]); acc[p][3] = fmaf(c.z, w2.w, acc[p][3]);
      acc[p][0] = fmaf(c.w, w3.x, acc[p][0]); acc[p][1] = fmaf(c.w, w3.y, acc[p][1]);
      acc[p][2] = fmaf(c.w, w3.z, acc[p][2]); acc[p][3] = fmaf(c.w, w3.w, acc[p][3]);
    }
  }
  float b0 = gld(UaC_b, a0+0, f32) + gld(UfC_b, a0+0, f32);
  float b1 = gld(UaC_b, a0+1, f32) + gld(UfC_b, a0+1, f32);
  float b2 = gld(UaC_b, a0+2, f32) + gld(UfC_b, a0+2, f32);
  float b3 = gld(UaC_b, a0+3, f32) + gld(UfC_b, a0+3, f32);
  #pragma unroll
  for (int p=0;p<16;p++){
    float4 v; v.x = acc[p][0]+b0; v.y = acc[p][1]+b1; v.z = acc[p][2]+b2; v.w = acc[p][3]+b3;
    *(float4*)&pctx[((size_t)(b*PP_ + pbase + pr + p))*512 + a0] = v;
  }
}

// ---------------- pre2: sb(768) + init(256) = 1024 blocks (AFTER k_pctx2)
__global__ __launch_bounds__(256) void k_pre2(
    const void* __restrict__ remb, const void* __restrict__ re_emb,
    const void* __restrict__ Wz, const void* __restrict__ bz,
    const void* __restrict__ Wr, const void* __restrict__ br,
    const void* __restrict__ Wh, const void* __restrict__ bhh,
    float* __restrict__ sb,
    float* __restrict__ buf, u32* __restrict__ sync, float* __restrict__ h,
    const void* __restrict__ init_state,
    const int* __restrict__ flag)
{
  const int f32 = flag[0];
  const int tid = threadIdx.x;
  int bid = blockIdx.x;
  if (bid < 768){
    __shared__ float emb[512];
    int g = bid >> 8;
    int tb = bid & 255; int t = tb >> 3; int b = tb & 7;
    emb[tid]     = gld(remb,   (size_t)(t*8+b)*256 + tid, f32);
    emb[tid+256] = gld(re_emb, (size_t)(t*8+b)*256 + tid, f32);
    __syncthreads();
    const void* W = (g==0?Wz:(g==1?Wr:Wh));
    const void* bias = (g==0?bz:(g==1?br:bhh));
    float acc = gld(bias, tid, f32) + dotw(W, (size_t)tid*512, emb, 512, f32);
    sb[(((size_t)g*32+t)*8+b)*256 + tid] = acc;
    return;
  }
  bid -= 768;
  {
    int i = bid*256 + tid;
    int stride = 256*256;
    for (int k=i; k<32*TB_*DD_; k+=stride) buf[k] = 0.f;
    for (int k=i; k<TB_*128;    k+=stride) sync[k] = 0u;
    for (int k=i; k<TB_*NN_;    k+=stride) h[k]   = gld(init_state, k, f32);
  }
}

// ---------------- persistent main: 256 blocks = 8 groups(b) x 32 (j); 256 threads
// R11's owner-sliced plane with ONE structural change: the ctC broadcast +
// its barrier are DELETED via the WCX identity
//   wc[n] = sum_d Wc[n,d]*ctC[d] = sum_p alpha[p] * WCX[n][p],
//   WCX[n][p] = sum_d Wc[n,d]*ctx[b,d,p]  (block-local, precomputed once into
//   LDS as bf16: 24 rows = 3 gates x own 8-n slice; ~31us init, inputs only,
//   so no cross-block coherence involved).
// FOUR barriers/step: B1 h0, B2 rawp, B3 e+psum, B4 h2.
// ctC still owner-computed for outputs (identical op order as R11).

__global__ __launch_bounds__(256, 1) void k_main(
    const void* __restrict__ ly_mask, const void* __restrict__ context, const void* __restrict__ cmask,
    const void* __restrict__ Uhz0, const void* __restrict__ Uhr0, const void* __restrict__ Uhh0,
    const void* __restrict__ WaC, const void* __restrict__ vaC_w, const void* __restrict__ vaC_b,
    const void* __restrict__ Uhz2, const void* __restrict__ Uhz2_b,
    const void* __restrict__ Uhr2, const void* __restrict__ Uhr2_b,
    const void* __restrict__ Uhh2, const void* __restrict__ Uhh2_b,
    const void* __restrict__ Wcz, const void* __restrict__ Wcr, const void* __restrict__ Wch,
    const int* __restrict__ rp,
    const float* __restrict__ pctx, const float* __restrict__ sb, const float* __restrict__ FKt,
    float* buf, float* h_ws, float* h0_ws, float* ealpha, float* rawp, u32* syncg,
    float* out, const int* __restrict__ flag)
{
  const int f32 = flag[0];
  const int tid = threadIdx.x;
  const int b = blockIdx.x >> 5;
  const int j = blockIdx.x & 31;
  const int ja = j >> 1, jp = j & 1;
  const int abase = ja*32;                    // 32-a slice for scores/query
  const int pbase = jp*288;                   // 288-p half for scores
  const int nbase = j*8;                      // 8-n slice for GRU gates
  const int dbase = j*21 + (j < 12 ? j : 12); // 22,22,..(x12),21,...(x20)
  const int dcnt  = (j < 12) ? 22 : 21;
  const int pown  = j*18;                     // 18-p e-window

  __shared__ float hprev[NN_], h0_lds[NN_];
  __shared__ float ap_lds[PP_], al_lds[PP_], cm_lds[PP_];
  __shared__ float fk_lds[9*32], vac_lds[32], q_lds[32], qpart[256];
  __shared__ float g1[24], u2l[24], wcl[24];
  __shared__ float red32[32];
  __shared__ float cs[8*576];                 // ctx chunk staging (WCX init only)
  __shared__ u16   wcx[24*576];               // bf16 WCX rows: [g*8+nl][p]

  for (int k=tid; k<288; k+=256) fk_lds[k] = FKt[(k>>5)*512 + abase + (k&31)];
  if (tid < 32) vac_lds[tid] = gld(vaC_w, abase + tid, f32);
  cm_lds[tid]     = gld(cmask, b*PP_ + tid, f32);
  cm_lds[tid+256] = gld(cmask, b*PP_ + tid + 256, f32);
  if (tid < 64) cm_lds[tid+512] = gld(cmask, b*PP_ + tid + 512, f32);
  ap_lds[tid] = 0.f; ap_lds[tid+256] = 0.f;
  if (tid < 64) ap_lds[tid+512] = 0.f;
  const float vb = gld(vaC_b, 0, f32);

  // ---- block-local WCX init: wcx[g*8+nl][p] = sum_d Wc_g[nbase+nl][d]*ctx[b][d][p]
  {
    const int nl = tid >> 5;          // 0..7
    const int pc = tid & 31;          // 32 chunks of 18 p
    for (int g=0; g<3; ++g){
      const void* W = (g==0 ? Wcz : (g==1 ? Wcr : Wch));
      float acc[18];
      #pragma unroll
      for (int i=0;i<18;i++) acc[i] = 0.f;
      for (int c=0; c<86; ++c){
        int d0 = c*8;
        int dc = (d0 + 8 <= DD_) ? 8 : (DD_ - d0);
        __syncthreads();   // protect cs from previous chunk's readers
        for (int k=tid; k<dc*576; k+=256){
          int dd = k / 576, p = k - dd*576;
          cs[dd*576 + p] = gld(context, ((size_t)(b*DD_ + d0 + dd))*PP_ + p, f32);
        }
        __syncthreads();
        #pragma unroll 1
        for (int dd=0; dd<dc; ++dd){
          float w = gld(W, (size_t)(nbase+nl)*DD_ + d0 + dd, f32);
          const float* cr = &cs[dd*576 + pc*18];
          #pragma unroll
          for (int i=0;i<18;i++) acc[i] = fmaf(w, cr[i], acc[i]);
        }
      }
      #pragma unroll
      for (int i=0;i<18;i++){
        u32 x = __float_as_uint(acc[i]);
        x += 0x7FFFu + ((x >> 16) & 1u);       // bf16 RNE
        wcx[(g*8 + nl)*576 + pc*18 + i] = (u16)(x >> 16);
      }
    }
  }
  __syncthreads();

  u32* ctr = syncg + b*128;
  float* psum_ws = (float*)(ctr + 96);   // 32 f32, two lines away from polled ctr line
  u32 bar_t = 0;
  const int p0 = tid, p1 = tid + 256, p2 = tid + 512;
  const bool has3 = (tid < 64);

  for (int t=0; t<32; t++){
    const float lm = gld(ly_mask, t*8+b, f32);

    //---- P1: stage h2(t-1); GRU1 n-slice (8 n, 8-lane dots); ctP owner chunk
    hprev[tid] = aload(&h_ws[b*256 + tid]);
    __syncthreads();
    if (tid < 192){
      int item = tid >> 3, q = tid & 7;        // 24 dots (3g x 8n), 8 lanes x 32 elems
      int g = item >> 3, nl = item & 7;
      int n = nbase + nl;
      const void* U = (g==0 ? Uhz0 : (g==1 ? Uhr0 : Uhh0));
      float acc = dotw(U, (size_t)n*256 + q*32, &hprev[q*32], 32, f32);
      acc += __shfl_xor(acc,1,64); acc += __shfl_xor(acc,2,64); acc += __shfl_xor(acc,4,64);
      if (q==0) g1[g*8+nl] = acc;
    }
    __syncthreads();
    if (tid < 8){
      int n = nbase + tid;
      float hp = hprev[n];
      float z0 = sigm(g1[tid]    + sb[(((size_t)t)*8+b)*256 + n]);
      float r0 = sigm(g1[8+tid]  + sb[(((size_t)(32+t))*8+b)*256 + n]);
      float hc = tanh_c(g1[16+tid]*r0 + sb[(((size_t)(64+t))*8+b)*256 + n]);
      float h0v = z0*hp + (1.f - z0)*hc;
      h0v = lm*h0v + (1.f - lm)*hp;
      astore(&h0_ws[b*256 + n], h0v);
    }
    {
      int rpos = rp[t*8+b];
      if ((unsigned)rpos > 31u) rpos = 31;
      if (tid < dcnt){
        int d = dbase + tid;
        out[OFF_CTP + (t*8+b)*DD_ + d] = aload(&buf[((size_t)rpos*8+b)*DD_ + d]);
      }
    }
    bar_t += 32; group_bar(ctr, bar_t);   // B1: h0 complete

    //---- P2: query (32 a) + scores (288 p x 32 a) + U2 dots
    h0_lds[tid] = aload(&h0_ws[b*256 + tid]);
    __syncthreads();
    {
      int ai = tid & 31, nb = tid >> 5;        // 8 x 32
      qpart[nb*32 + ai] = dotw(WaC, (size_t)(abase+ai)*256 + nb*32, &h0_lds[nb*32], 32, f32);
    }
    __syncthreads();
    if (tid < 32){
      float qv = 0.f;
      #pragma unroll
      for (int nb2=0;nb2<8;nb2++) qv += qpart[nb2*32 + tid];
      q_lds[tid] = qv;
    }
    __syncthreads();
    #pragma unroll 1
    for (int round=0; round<2; round++){
      int item = tid + round*256;              // 288 items = 288 p
      if (item >= 288) break;
      int p = pbase + item;
      float PQ[32];
      const float* pc = pctx + ((size_t)(b*PP_ + p))*512 + abase;
      #pragma unroll
      for (int q8=0;q8<8;q8++){
        float4 u = *(const float4*)(pc + q8*4);
        PQ[q8*4+0]=u.x; PQ[q8*4+1]=u.y; PQ[q8*4+2]=u.z; PQ[q8*4+3]=u.w;
      }
      int hh_ = p / 48, ww_ = p - hh_*48;
      #pragma unroll
      for (int kh=0;kh<3;kh++){
        int h2_ = hh_ + kh - 1;
        if ((unsigned)h2_ >= 12u) continue;
        #pragma unroll
        for (int kw=0;kw<3;kw++){
          int w2_ = ww_ + kw - 1;
          if ((unsigned)w2_ >= 48u) continue;
          float av = ap_lds[h2_*48 + w2_];
          const float* fkp = &fk_lds[(kh*3+kw)*32];
          #pragma unroll
          for (int ai=0;ai<32;ai++) PQ[ai] = fmaf(av, fkp[ai], PQ[ai]);
        }
      }
      float racc = 0.f;
      #pragma unroll
      for (int ai=0;ai<32;ai++)
        racc = fmaf(vac_lds[ai], tanh_c(PQ[ai] + q_lds[ai]), racc);
      astore(&rawp[((size_t)(b*16 + ja))*PP_ + p], racc);
    }
    if (tid < 192){
      int item = tid >> 3, q = tid & 7;
      int g = item >> 3, nl = item & 7;
      int n = nbase + nl;
      const void* U = (g==0 ? Uhz2 : (g==1 ? Uhr2 : Uhh2));
      float acc = dotw(U, (size_t)n*256 + q*32, &h0_lds[q*32], 32, f32);
      acc += __shfl_xor(acc,1,64); acc += __shfl_xor(acc,2,64); acc += __shfl_xor(acc,4,64);
      if (q==0) u2l[g*8+nl] = acc;
    }
    bar_t += 32; group_bar(ctr, bar_t);   // B2: rawp complete

    //---- P3: owner reduce of own 18-p window -> e chunk + 1 psum
    {
      float ev = 0.f;
      if (tid < 18){
        int p = pown + tid;
        float raw = vb;
        #pragma unroll
        for (int j2=0;j2<16;j2++) raw += aload(&rawp[((size_t)(b*16+j2))*PP_ + p]);
        raw = fminf(fmaxf(raw, -60.f), 60.f);
        ev = __expf(raw) * cm_lds[p];
        astore(&ealpha[b*PP_ + p], ev);
      }
      if (tid < 64){
        float s = ev;
        #pragma unroll
        for (int off=1; off<64; off<<=1) s += __shfl_xor(s, off, 64);
        if (tid == 0) astore(&psum_ws[j], s);
      }
    }
    bar_t += 32; group_bar(ctr, bar_t);   // B3: e + psums complete

    //---- P4: broadcast e + 32 psums, normalize, ap update, outputs, ctC owner
    //         chunk, wc via WCX (no ctC broadcast), h2 combine
    {
      float e0 = aload(&ealpha[b*PP_ + p0]);
      float e1 = aload(&ealpha[b*PP_ + p1]);
      float e2 = has3 ? aload(&ealpha[b*PP_ + p2]) : 0.f;
      if (tid < 32) red32[tid] = aload(&psum_ws[tid]);
      __syncthreads();
      float S = 0.f;
      #pragma unroll
      for (int k=0;k<32;k++) S += red32[k];
      S = fmaxf(S, 1e-30f);
      float inv = rcpf(S);
      float a0 = e0*inv + 1e-10f; al_lds[p0] = a0; ap_lds[p0] += a0;
      float a1 = e1*inv + 1e-10f; al_lds[p1] = a1; ap_lds[p1] += a1;
      if (has3){ float a2 = e2*inv + 1e-10f; al_lds[p2] = a2; ap_lds[p2] += a2; }
    }
    __syncthreads();
    if (tid < 18){
      int p = pown + tid;
      out[OFF_AL  + (t*8+b)*PP_ + p] = al_lds[p];
      out[OFF_APO + (t*8+b)*PP_ + p] = ap_lds[p];
    }
    {
      int dd = tid >> 2, q = tid & 3;
      if (dd < dcnt){
        int d = dbase + dd;
        float acc;
        if (f32) acc = dotf((const float*)context + ((size_t)(b*DD_+d))*PP_ + q*144, &al_lds[q*144], 144);
        else {
          const u16* crow = (const u16*)context + ((size_t)(b*DD_+d))*PP_ + q*144;
          acc = 0.f;
          #pragma unroll 6
          for (int k=0;k<144;k+=8) acc += dot8(*(const uint4*)(crow+k), &al_lds[q*144+k]);
        }
        acc += __shfl_xor(acc,1,64); acc += __shfl_xor(acc,2,64);
        if (q==0){
          astore(&out[OFF_CTC + (t*8+b)*DD_ + d], acc);
          if (t < 31) astore(&buf[(((size_t)(t+1))*8+b)*DD_ + d], acc);  // row 32 never read
        }
      }
    }
    if (tid < 192){   // wc[g][nl] = sum_p alpha[p]*wcx[g*8+nl][p]; 8 lanes x 72
      int row = tid >> 3, q = tid & 7;
      const u16* wr = &wcx[row*576 + q*72];
      const float* ar = &al_lds[q*72];
      float acc = 0.f;
      #pragma unroll
      for (int i=0;i<72;i+=8) acc += dot8(*(const uint4*)(wr+i), ar+i);
      acc += __shfl_xor(acc,1,64); acc += __shfl_xor(acc,2,64); acc += __shfl_xor(acc,4,64);
      if (q==0) wcl[row] = acc;
    }
    __syncthreads();
    if (tid < 8){
      int n = nbase + tid;
      float h0v = h0_lds[n];
      float z2 = sigm(u2l[tid]   + gld(Uhz2_b, n, f32) + wcl[tid]);
      float r2 = sigm(u2l[8+tid] + gld(Uhr2_b, n, f32) + wcl[8+tid]);
      float hc = tanh_c((u2l[16+tid] + gld(Uhh2_b, n, f32))*r2 + wcl[16+tid]);
      float h2v = z2*h0v + (1.f - z2)*hc;
      h2v = lm*h2v + (1.f - lm)*h0v;
      astore(&h_ws[b*256 + n], h2v);
      out[OFF_H2 + (t*8+b)*256 + n] = h2v;
    }
    bar_t += 32; group_bar(ctr, bar_t);   // B4: h2 complete
  }
}

// ---------------- host ----------------

extern "C" void kernel_launch(void* const* d_in, const int* in_sizes, int n_in,
                              void* d_out, int out_size, void* d_ws, size_t ws_size,
                              hipStream_t stream){
  (void)in_sizes; (void)n_in; (void)out_size;
  if (ws_size < WS_NEED) return;

  const void* remb       = d_in[0];
  const void* re_emb     = d_in[1];
  const void* ly_mask    = d_in[2];
  const void* context    = d_in[3];
  const void* cmask      = d_in[4];
  const void* init_state = d_in[5];
  const void* Wyz_w = d_in[6];  const void* Wyz_b = d_in[7];
  const void* Wyr_w = d_in[8];  const void* Wyr_b = d_in[9];
  const void* Wyh_w = d_in[10]; const void* Wyh_b = d_in[11];
  const void* Uhz0  = d_in[12];
  const void* Uhr0  = d_in[13];
  const void* Uhh0  = d_in[14];
  const void* UaC_w = d_in[15]; const void* UaC_b = d_in[16];
  const void* WaC_w = d_in[17];
  const void* QC_w  = d_in[18];
  const void* UfC_w = d_in[19]; const void* UfC_b = d_in[20];
  const void* vaC_w = d_in[21]; const void* vaC_b = d_in[22];
  const void* Uhz2  = d_in[23]; const void* Uhz2_b = d_in[24];
  const void* Uhr2  = d_in[25]; const void* Uhr2_b = d_in[26];
  const void* Uhh2  = d_in[27]; const void* Uhh2_b = d_in[28];
  const void* Wcz   = d_in[29];
  const void* Wcr   = d_in[30];
  const void* Wch   = d_in[31];
  const int*  rp    = (const int*)d_in[32];

  char* ws = (char*)d_ws;
  float* sbp   = (float*)(ws + OFF_SB);
  float* UaCT  = (float*)(ws + OFF_TRAN);
  float* buf   = (float*)(ws + OFF_BUF);
  float* pctx  = (float*)(ws + OFF_PCTX);
  float* FKt   = (float*)(ws + OFF_FKT);
  float* rawp  = (float*)(ws + OFF_RAWP);
  float* h_ws  = (float*)(ws + OFF_H);
  float* h0_ws = (float*)(ws + OFF_H0);
  float* eal   = (float*)(ws + OFF_EAL);
  u32*   syncg = (u32*)  (ws + OFF_SYNC);
  int*   flag  = (int*)  (ws + OFF_FLG);
  float* out   = (float*)d_out;

  k_detect<<<1, 256, 0, stream>>>((const u16*)context, flag);
  k_pre1 <<<120, 256, 0, stream>>>(UaC_w, UaCT, QC_w, UfC_w, FKt, flag);
  k_pctx2<<<144, 256, 0, stream>>>(context, UaCT, UaC_b, UfC_b, pctx, flag);
  // region0 reuse: UaCT dead after k_pctx2 -> sb/buf may now overwrite it
  k_pre2 <<<1024, 256, 0, stream>>>(remb, re_emb, Wyz_w, Wyz_b, Wyr_w, Wyr_b, Wyh_w, Wyh_b, sbp,
                                    buf, syncg, h_ws, init_state, flag);
  k_main <<<256, 256, 0, stream>>>(ly_mask, context, cmask,
                                   Uhz0, Uhr0, Uhh0, WaC_w, vaC_w, vaC_b,
                                   Uhz2, Uhz2_b, Uhr2, Uhr2_b, Uhh2, Uhh2_b,
                                   Wcz, Wcr, Wch, rp,
                                   pctx, sbp, FKt,
                                   buf, h_ws, h0_ws, eal, rawp, syncg, out, flag);
}

// Round 16
// 1078.577 us; speedup vs baseline: 2.3060x; 2.3060x over previous
//
#include <hip/hip_runtime.h>
#include <stdint.h>

typedef unsigned short u16;
typedef unsigned int   u32;

// problem dims
#define TB_ 8      // batch
#define NN_ 256    // state n
#define DD_ 684    // context depth d
#define PP_ 576    // H*W = 12*48

// workspace layout (bytes). Region0 [0, 1486848) time-shared BY LAUNCH ORDER:
//   phase1: UaCT (f32 [684][512]) @0        -- k_pre1 writes, k_pctx2 reads
//   phase2: sb @0 + buf @786432             -- k_pre2 writes AFTER k_pctx2 consumed UaCT
#define OFF_SB    0u
#define OFF_TRAN  0u
#define OFF_BUF   786432u
#define OFF_PCTX  1486848u    // f32 [b][p(576)][a(512)]
#define OFF_FKT   10924032u   // f32 [tap(9)][a(512)]
#define OFF_RAWP  10942464u   // f32 [b][ja(16)][p(576)]; row ja written by 2 blocks (p-halves)
#define OFF_H     11237376u   // f32 [b][n]
#define OFF_H0    11245568u   // f32 [b][n]
#define OFF_EAL   11253760u   // (unused this rev)
#define OFF_SYNC  11272192u   // u32 [b][128]: [0]=barrier ctr
#define OFF_FLG   11276288u   // int dtype flag
#define WS_NEED   11276304u

// output offsets (elements, f32)
#define OFF_H2   0
#define OFF_CTC  65536
#define OFF_CTP  240640
#define OFF_AL   415744
#define OFF_APO  563200

__device__ __forceinline__ float b2f(u16 v){ union{u32 i; float f;} x; x.i = ((u32)v)<<16; return x.f; }
__device__ __forceinline__ float gld(const void* p, size_t i, int f32){
  if (f32) return ((const float*)p)[i];
  return b2f(((const u16*)p)[i]);
}
__device__ __forceinline__ float bl(u32 v){ union{u32 i; float f;} x; x.i = v<<16; return x.f; }
__device__ __forceinline__ float bh(u32 v){ union{u32 i; float f;} x; x.i = v & 0xFFFF0000u; return x.f; }

// coherence-point (L3) scalar access for cross-block data.
__device__ __forceinline__ float aload(const float* p){
  u32 v = __hip_atomic_load((const u32*)p, __ATOMIC_RELAXED, __HIP_MEMORY_SCOPE_AGENT);
  union{u32 i; float f;} x; x.i = v; return x.f;
}
__device__ __forceinline__ void astore(float* p, float v){
  union{float f; u32 i;} x; x.f = v;
  __hip_atomic_store((u32*)p, x.i, __ATOMIC_RELAXED, __HIP_MEMORY_SCOPE_AGENT);
}

__device__ __forceinline__ float rcpf(float x){ return __builtin_amdgcn_rcpf(x); }
__device__ __forceinline__ float sigm(float x){
  x = fminf(fmaxf(x, -30.f), 30.f);
  return rcpf(1.f + __expf(-x));
}
__device__ __forceinline__ float tanh_c(float x){
  x = fminf(fmaxf(x, -15.f), 15.f);
  float e = __expf(2.f*x);
  return 1.f - 2.f*rcpf(e + 1.f);
}

__device__ __forceinline__ float dot8(uint4 u, const float* s){
  float a = fmaf(bl(u.x), s[0], bh(u.x)*s[1]);
  a = fmaf(bl(u.y), s[2], a); a = fmaf(bh(u.y), s[3], a);
  a = fmaf(bl(u.z), s[4], a); a = fmaf(bh(u.z), s[5], a);
  a = fmaf(bl(u.w), s[6], a); a = fmaf(bh(u.w), s[7], a);
  return a;
}
__device__ __forceinline__ float dot4t(uint2 u, const float* s, float a){
  a = fmaf(bl(u.x), s[0], a); a = fmaf(bh(u.x), s[1], a);
  a = fmaf(bl(u.y), s[2], a); a = fmaf(bh(u.y), s[3], a);
  return a;
}
__device__ __forceinline__ float dotf(const float* w, const float* s, int n){
  float a = 0.f;
  #pragma unroll 4
  for (int k=0;k<n;k+=4){
    float4 u = *(const float4*)(w+k);
    a = fmaf(u.x, s[k], a);   a = fmaf(u.y, s[k+1], a);
    a = fmaf(u.z, s[k+2], a); a = fmaf(u.w, s[k+3], a);
  }
  return a;
}
// n must be a multiple of 4
__device__ __forceinline__ float dotw(const void* W, size_t row_off, const float* s, int n, int f32){
  if (f32) return dotf((const float*)W + row_off, s, n);
  const u16* r = (const u16*)W + row_off;
  float a = 0.f;
  int k = 0;
  for (; k+8 <= n; k += 8) a += dot8(*(const uint4*)(r+k), s+k);
  if (k < n) a = dot4t(*(const uint2*)(r+k), s+k, a);
  return a;
}

// counter barrier (R1 primitive, zero outliers): __syncthreads drains all waves'
// vmem (compiler emits vmcnt(0) before s_barrier); tid0 RMW + throttled poll.
__device__ __forceinline__ void group_bar(u32* ctr, u32 target){
  __syncthreads();
  if (threadIdx.x == 0){
    __hip_atomic_fetch_add(ctr, 1u, __ATOMIC_RELAXED, __HIP_MEMORY_SCOPE_AGENT);
    while (__hip_atomic_load(ctr, __ATOMIC_RELAXED, __HIP_MEMORY_SCOPE_AGENT) < target)
      __builtin_amdgcn_s_sleep(2);
  }
  __syncthreads();
}

// ---------------- dtype detector ----------------
__global__ void k_detect(const u16* __restrict__ ctx_u16, int* __restrict__ flag){
  __shared__ int cnt;
  if (threadIdx.x == 0) cnt = 0;
  __syncthreads();
  int bad = 0;
  for (int k = threadIdx.x; k < 512; k += 256){
    u16 v = ctx_u16[k];
    int e = (v >> 7) & 0xFF;
    bool sane = (v == 0u) || (v == 0x8000u) || (e >= 102 && e <= 141);
    if (!sane) bad++;
  }
  atomicAdd(&cnt, bad);
  __syncthreads();
  if (threadIdx.x == 0) flag[0] = (cnt > 64) ? 1 : 0;
}

// ---------------- pre1: tran(88) + fk(32) = 120 blocks (runs BEFORE k_pctx2)
__global__ __launch_bounds__(256) void k_pre1(
    const void* __restrict__ UaC_w, float* __restrict__ UaCT,
    const void* __restrict__ QC, const void* __restrict__ UfC, float* __restrict__ FKt,
    const int* __restrict__ flag)
{
  const int f32 = flag[0];
  const int tid = threadIdx.x;
  __shared__ float smem[4608];
  int bid = blockIdx.x;

  if (bid < 88){
    int ab = bid / 11, db = bid - ab*11;
    int tc = tid & 63, tr = tid >> 6;
    int d0 = db*64, a0 = ab*64;
    for (int rr = tr; rr < 64; rr += 4){
      int d = d0 + tc;
      if (d < DD_) smem[rr*65 + tc] = gld(UaC_w, (size_t)(a0+rr)*DD_ + d, f32);
    }
    __syncthreads();
    for (int rr = tr; rr < 64; rr += 4){
      int d = d0 + rr;
      if (d < DD_) UaCT[(size_t)d*512 + a0 + tc] = smem[tc*65 + rr];
    }
    return;
  }
  bid -= 88;
  {
    for (int k=tid;k<4608;k+=256) smem[k] = gld(QC, k, f32);
    __syncthreads();
    const int lane = tid & 63;
    const int wid = bid*4 + (tid>>6);
    for (int rr=0; rr<4; rr++){
      const int a = wid*4 + rr;
      float acc[9];
      #pragma unroll
      for (int tt=0;tt<9;tt++) acc[tt]=0.f;
      #pragma unroll
      for (int k=0;k<8;k++){
        int c = lane + k*64;
        float v = gld(UfC, (size_t)a*512 + c, f32);
        const float* q = &smem[c*9];
        #pragma unroll
        for (int tt=0;tt<9;tt++) acc[tt] = fmaf(v, q[tt], acc[tt]);
      }
      #pragma unroll
      for (int off=1; off<64; off<<=1){
        #pragma unroll
        for (int tt=0;tt<9;tt++) acc[tt] += __shfl_xor(acc[tt], off, 64);
      }
      #pragma unroll
      for (int tt=0;tt<9;tt++) if (lane == tt) FKt[tt*512 + a] = acc[tt];
    }
  }
}

// pctx[b][p][a] = context[b,:,p].UaC[a,:] + UaC_b[a] + UfC_b[a]
__global__ __launch_bounds__(256) void k_pctx2(const void* __restrict__ context,
    const float* __restrict__ UaCT, const void* __restrict__ UaC_b, const void* __restrict__ UfC_b,
    float* __restrict__ pctx, const int* __restrict__ flag){
  const int f32 = flag[0];
  const int blk = blockIdx.x;
  const int b = blk / 18;
  const int pbase = (blk - b*18) * 32;
  __shared__ float ctx[32][DD_];
  const int tid = threadIdx.x;
  for (int k=tid; k<32*DD_; k+=256){
    int p = k & 31, d = k >> 5;
    ctx[p][d] = gld(context, ((size_t)(b*DD_+d))*PP_ + pbase + p, f32);
  }
  __syncthreads();
  const int a0 = (tid & 127) * 4;
  const int pr = (tid >> 7) * 16;
  float acc[16][4];
  #pragma unroll
  for (int p=0;p<16;p++){ acc[p][0]=0.f; acc[p][1]=0.f; acc[p][2]=0.f; acc[p][3]=0.f; }
  for (int d=0; d<DD_; d+=4){
    float4 w0 = *(const float4*)&UaCT[(size_t)(d+0)*512 + a0];
    float4 w1 = *(const float4*)&UaCT[(size_t)(d+1)*512 + a0];
    float4 w2 = *(const float4*)&UaCT[(size_t)(d+2)*512 + a0];
    float4 w3 = *(const float4*)&UaCT[(size_t)(d+3)*512 + a0];
    #pragma unroll
    for (int p=0;p<16;p++){
      float4 c = *(const float4*)(&ctx[pr+p][d]);
      acc[p][0] = fmaf(c.x, w0.x, acc[p][0]); acc[p][1] = fmaf(c.x, w0.y, acc[p][1]);
      acc[p][2] = fmaf(c.x, w0.z, acc[p][2]); acc[p][3] = fmaf(c.x, w0.w, acc[p][3]);
      acc[p][0] = fmaf(c.y, w1.x, acc[p][0]); acc[p][1] = fmaf(c.y, w1.y, acc[p][1]);
      acc[p][2] = fmaf(c.y, w1.z, acc[p][2]); acc[p][3] = fmaf(c.y, w1.w, acc[p][3]);
      acc[p][0] = fmaf(c.z, w2.x, acc[p][0]); acc[p][1] = fmaf(c.z, w2.y, acc[p][1]);
      acc[p][2] = fmaf(c.z, w2.z, acc[p][2]); acc[p][3] = fmaf(c.z, w2.w, acc[p][3]);
      acc[p][0] = fmaf(c.w, w3.x, acc[p][0]); acc[p][1] = fmaf(c.w, w3.y, acc[p][1]);
      acc[p][2] = fmaf(c.w, w3.z, acc[p][2]); acc[p][3] = fmaf(c.w, w3.w, acc[p][3]);
    }
  }
  float b0 = gld(UaC_b, a0+0, f32) + gld(UfC_b, a0+0, f32);
  float b1 = gld(UaC_b, a0+1, f32) + gld(UfC_b, a0+1, f32);
  float b2 = gld(UaC_b, a0+2, f32) + gld(UfC_b, a0+2, f32);
  float b3 = gld(UaC_b, a0+3, f32) + gld(UfC_b, a0+3, f32);
  #pragma unroll
  for (int p=0;p<16;p++){
    float4 v; v.x = acc[p][0]+b0; v.y = acc[p][1]+b1; v.z = acc[p][2]+b2; v.w = acc[p][3]+b3;
    *(float4*)&pctx[((size_t)(b*PP_ + pbase + pr + p))*512 + a0] = v;
  }
}

// ---------------- pre2: sb(768) + init(256) = 1024 blocks (AFTER k_pctx2)
__global__ __launch_bounds__(256) void k_pre2(
    const void* __restrict__ remb, const void* __restrict__ re_emb,
    const void* __restrict__ Wz, const void* __restrict__ bz,
    const void* __restrict__ Wr, const void* __restrict__ br,
    const void* __restrict__ Wh, const void* __restrict__ bhh,
    float* __restrict__ sb,
    float* __restrict__ buf, u32* __restrict__ sync, float* __restrict__ h,
    const void* __restrict__ init_state,
    const int* __restrict__ flag)
{
  const int f32 = flag[0];
  const int tid = threadIdx.x;
  int bid = blockIdx.x;
  if (bid < 768){
    __shared__ float emb[512];
    int g = bid >> 8;
    int tb = bid & 255; int t = tb >> 3; int b = tb & 7;
    emb[tid]     = gld(remb,   (size_t)(t*8+b)*256 + tid, f32);
    emb[tid+256] = gld(re_emb, (size_t)(t*8+b)*256 + tid, f32);
    __syncthreads();
    const void* W = (g==0?Wz:(g==1?Wr:Wh));
    const void* bias = (g==0?bz:(g==1?br:bhh));
    float acc = gld(bias, tid, f32) + dotw(W, (size_t)tid*512, emb, 512, f32);
    sb[(((size_t)g*32+t)*8+b)*256 + tid] = acc;
    return;
  }
  bid -= 768;
  {
    int i = bid*256 + tid;
    int stride = 256*256;
    for (int k=i; k<32*TB_*DD_; k+=stride) buf[k] = 0.f;
    for (int k=i; k<TB_*128;    k+=stride) sync[k] = 0u;
    for (int k=i; k<TB_*NN_;    k+=stride) h[k]   = gld(init_state, k, f32);
  }
}

// ---------------- persistent main: 256 blocks = 8 groups(b) x 32 (j); 256 threads
// R11's owner-sliced plane with the e-exchange MERGED into the alpha phase:
// FOUR barriers/step: B1 h0, B2 rawp, B3 ctC, B4 h2.
// After B2, every block gathers all 16 rawp rows (36.9KB) with NINE pipelined
// global_load_dwordx4 sc0 sc1 per thread (vs R6's 9216 scalar aloads -- 4x
// fewer L3 transactions, issued back-to-back), stages into LDS, then computes
// e/S/alpha/ap locally in identical op order => bitwise-identical across
// blocks. Deletes the owner-e phase, its barrier, and the ealpha/psum plumbing.

__global__ __launch_bounds__(256, 1) void k_main(
    const void* __restrict__ ly_mask, const void* __restrict__ context, const void* __restrict__ cmask,
    const void* __restrict__ Uhz0, const void* __restrict__ Uhr0, const void* __restrict__ Uhh0,
    const void* __restrict__ WaC, const void* __restrict__ vaC_w, const void* __restrict__ vaC_b,
    const void* __restrict__ Uhz2, const void* __restrict__ Uhz2_b,
    const void* __restrict__ Uhr2, const void* __restrict__ Uhr2_b,
    const void* __restrict__ Uhh2, const void* __restrict__ Uhh2_b,
    const void* __restrict__ Wcz, const void* __restrict__ Wcr, const void* __restrict__ Wch,
    const int* __restrict__ rp,
    const float* __restrict__ pctx, const float* __restrict__ sb, const float* __restrict__ FKt,
    float* buf, float* h_ws, float* h0_ws, float* rawp, u32* syncg,
    float* out, const int* __restrict__ flag)
{
  const int f32 = flag[0];
  const int tid = threadIdx.x;
  const int b = blockIdx.x >> 5;
  const int j = blockIdx.x & 31;
  const int ja = j >> 1, jp = j & 1;
  const int abase = ja*32;                    // 32-a slice for scores/query
  const int pbase = jp*288;                   // 288-p half for scores
  const int nbase = j*8;                      // 8-n slice for GRU gates
  const int dbase = j*21 + (j < 12 ? j : 12); // 22,22,..(x12),21,...(x20)
  const int dcnt  = (j < 12) ? 22 : 21;
  const int pown  = j*18;                     // 18-p AL/APO owner window

  __shared__ float hprev[NN_], h0_lds[NN_];
  __shared__ float ap_lds[PP_], al_lds[PP_], cm_lds[PP_];
  __shared__ float ctc_lds[DD_];
  __shared__ float fk_lds[9*32], vac_lds[32], q_lds[32], qpart[256];
  __shared__ float g1[24], u2l[24], wcl[24];
  __shared__ float red[4];
  __shared__ float sp[16*PP_];                // staged rawp [j2][p] (36.9 KB)

  for (int k=tid; k<288; k+=256) fk_lds[k] = FKt[(k>>5)*512 + abase + (k&31)];
  if (tid < 32) vac_lds[tid] = gld(vaC_w, abase + tid, f32);
  cm_lds[tid]     = gld(cmask, b*PP_ + tid, f32);
  cm_lds[tid+256] = gld(cmask, b*PP_ + tid + 256, f32);
  if (tid < 64) cm_lds[tid+512] = gld(cmask, b*PP_ + tid + 512, f32);
  ap_lds[tid] = 0.f; ap_lds[tid+256] = 0.f;
  if (tid < 64) ap_lds[tid+512] = 0.f;
  const float vb = gld(vaC_b, 0, f32);

  u32* ctr = syncg + b*128;
  u32 bar_t = 0;
  const int p0 = tid, p1 = tid + 256, p2 = tid + 512;
  const bool has3 = (tid < 64);

  for (int t=0; t<32; t++){
    const float lm = gld(ly_mask, t*8+b, f32);

    //---- P1: stage h2(t-1); GRU1 n-slice (8 n, 8-lane dots); ctP owner chunk
    hprev[tid] = aload(&h_ws[b*256 + tid]);
    __syncthreads();
    if (tid < 192){
      int item = tid >> 3, q = tid & 7;        // 24 dots (3g x 8n), 8 lanes x 32 elems
      int g = item >> 3, nl = item & 7;
      int n = nbase + nl;
      const void* U = (g==0 ? Uhz0 : (g==1 ? Uhr0 : Uhh0));
      float acc = dotw(U, (size_t)n*256 + q*32, &hprev[q*32], 32, f32);
      acc += __shfl_xor(acc,1,64); acc += __shfl_xor(acc,2,64); acc += __shfl_xor(acc,4,64);
      if (q==0) g1[g*8+nl] = acc;
    }
    __syncthreads();
    if (tid < 8){
      int n = nbase + tid;
      float hp = hprev[n];
      float z0 = sigm(g1[tid]    + sb[(((size_t)t)*8+b)*256 + n]);
      float r0 = sigm(g1[8+tid]  + sb[(((size_t)(32+t))*8+b)*256 + n]);
      float hc = tanh_c(g1[16+tid]*r0 + sb[(((size_t)(64+t))*8+b)*256 + n]);
      float h0v = z0*hp + (1.f - z0)*hc;
      h0v = lm*h0v + (1.f - lm)*hp;
      astore(&h0_ws[b*256 + n], h0v);
    }
    {
      int rpos = rp[t*8+b];
      if ((unsigned)rpos > 31u) rpos = 31;
      if (tid < dcnt){
        int d = dbase + tid;
        out[OFF_CTP + (t*8+b)*DD_ + d] = aload(&buf[((size_t)rpos*8+b)*DD_ + d]);
      }
    }
    bar_t += 32; group_bar(ctr, bar_t);   // B1: h0 complete

    //---- P2: query (32 a) + scores (288 p x 32 a) + U2 dots
    h0_lds[tid] = aload(&h0_ws[b*256 + tid]);
    __syncthreads();
    {
      int ai = tid & 31, nb = tid >> 5;        // 8 x 32
      qpart[nb*32 + ai] = dotw(WaC, (size_t)(abase+ai)*256 + nb*32, &h0_lds[nb*32], 32, f32);
    }
    __syncthreads();
    if (tid < 32){
      float qv = 0.f;
      #pragma unroll
      for (int nb2=0;nb2<8;nb2++) qv += qpart[nb2*32 + tid];
      q_lds[tid] = qv;
    }
    __syncthreads();
    #pragma unroll 1
    for (int round=0; round<2; round++){
      int item = tid + round*256;              // 288 items = 288 p
      if (item >= 288) break;
      int p = pbase + item;
      float PQ[32];
      const float* pc = pctx + ((size_t)(b*PP_ + p))*512 + abase;
      #pragma unroll
      for (int q8=0;q8<8;q8++){
        float4 u = *(const float4*)(pc + q8*4);
        PQ[q8*4+0]=u.x; PQ[q8*4+1]=u.y; PQ[q8*4+2]=u.z; PQ[q8*4+3]=u.w;
      }
      int hh_ = p / 48, ww_ = p - hh_*48;
      #pragma unroll
      for (int kh=0;kh<3;kh++){
        int h2_ = hh_ + kh - 1;
        if ((unsigned)h2_ >= 12u) continue;
        #pragma unroll
        for (int kw=0;kw<3;kw++){
          int w2_ = ww_ + kw - 1;
          if ((unsigned)w2_ >= 48u) continue;
          float av = ap_lds[h2_*48 + w2_];
          const float* fkp = &fk_lds[(kh*3+kw)*32];
          #pragma unroll
          for (int ai=0;ai<32;ai++) PQ[ai] = fmaf(av, fkp[ai], PQ[ai]);
        }
      }
      float racc = 0.f;
      #pragma unroll
      for (int ai=0;ai<32;ai++)
        racc = fmaf(vac_lds[ai], tanh_c(PQ[ai] + q_lds[ai]), racc);
      astore(&rawp[((size_t)(b*16 + ja))*PP_ + p], racc);
    }
    if (tid < 192){
      int item = tid >> 3, q = tid & 7;
      int g = item >> 3, nl = item & 7;
      int n = nbase + nl;
      const void* U = (g==0 ? Uhz2 : (g==1 ? Uhr2 : Uhh2));
      float acc = dotw(U, (size_t)n*256 + q*32, &h0_lds[q*32], 32, f32);
      acc += __shfl_xor(acc,1,64); acc += __shfl_xor(acc,2,64); acc += __shfl_xor(acc,4,64);
      if (q==0) u2l[g*8+nl] = acc;
    }
    bar_t += 32; group_bar(ctr, bar_t);   // B2: rawp complete

    //---- P3: wide coherent gather of all 16 rawp rows -> LDS; replicated
    //         e/S/alpha/ap (identical op order in every block); owner AL/APO;
    //         ctC owner d-chunk
    {
      const float* base = rawp + (size_t)b*16*PP_ + tid*4;
      float4 rv[9];
      #pragma unroll
      for (int k=0;k<9;k++){
        asm volatile("global_load_dwordx4 %0, %1, off sc0 sc1"
                     : "=&v"(rv[k]) : "v"(base + k*1024) : "memory");
      }
      asm volatile("s_waitcnt vmcnt(0)" ::: "memory");
      __builtin_amdgcn_sched_barrier(0);
      #pragma unroll
      for (int k=0;k<9;k++) *(float4*)&sp[tid*4 + k*1024] = rv[k];
    }
    __syncthreads();
    {
      float psum = 0.f;
      #pragma unroll 1
      for (int rep=0; rep<3; rep++){
        int p = tid + rep*256;
        if (p >= PP_) break;
        float raw = vb;
        #pragma unroll
        for (int j2=0;j2<16;j2++) raw += sp[j2*PP_ + p];
        raw = fminf(fmaxf(raw, -60.f), 60.f);
        float e = __expf(raw) * cm_lds[p];
        al_lds[p] = e; psum += e;
      }
      #pragma unroll
      for (int off=1; off<64; off<<=1) psum += __shfl_xor(psum, off, 64);
      if ((tid & 63)==0) red[tid>>6] = psum;
    }
    __syncthreads();
    {
      float S = red[0] + red[1] + red[2] + red[3];
      S = fmaxf(S, 1e-30f);
      float inv = rcpf(S);
      float a0 = al_lds[p0]*inv + 1e-10f; al_lds[p0] = a0; ap_lds[p0] += a0;
      float a1 = al_lds[p1]*inv + 1e-10f; al_lds[p1] = a1; ap_lds[p1] += a1;
      if (has3){ float a2 = al_lds[p2]*inv + 1e-10f; al_lds[p2] = a2; ap_lds[p2] += a2; }
    }
    __syncthreads();
    if (tid < 18){
      int p = pown + tid;
      out[OFF_AL  + (t*8+b)*PP_ + p] = al_lds[p];
      out[OFF_APO + (t*8+b)*PP_ + p] = ap_lds[p];
    }
    {
      int dd = tid >> 2, q = tid & 3;
      if (dd < dcnt){
        int d = dbase + dd;
        float acc;
        if (f32) acc = dotf((const float*)context + ((size_t)(b*DD_+d))*PP_ + q*144, &al_lds[q*144], 144);
        else {
          const u16* crow = (const u16*)context + ((size_t)(b*DD_+d))*PP_ + q*144;
          acc = 0.f;
          #pragma unroll 6
          for (int k=0;k<144;k+=8) acc += dot8(*(const uint4*)(crow+k), &al_lds[q*144+k]);
        }
        acc += __shfl_xor(acc,1,64); acc += __shfl_xor(acc,2,64);
        if (q==0){
          astore(&out[OFF_CTC + (t*8+b)*DD_ + d], acc);
          if (t < 31) astore(&buf[(((size_t)(t+1))*8+b)*DD_ + d], acc);  // row 32 never read
        }
      }
    }
    bar_t += 32; group_bar(ctr, bar_t);   // B3: ctC complete

    //---- P4: ctC broadcast, Wc dots (8-lane chunks 88.. + 68), h2 combine
    for (int k=tid; k<DD_; k+=256) ctc_lds[k] = aload(&out[OFF_CTC + (t*8+b)*DD_ + k]);
    __syncthreads();
    if (tid < 192){
      int item = tid >> 3, q = tid & 7;        // 24 dots (3g x 8n), 8 lanes
      int g = item >> 3, nl = item & 7;
      int n = nbase + nl;
      const void* W = (g==0 ? Wcz : (g==1 ? Wcr : Wch));
      int base = q*88, cnt = (q==7) ? 68 : 88;
      float acc = dotw(W, (size_t)n*DD_ + base, &ctc_lds[base], cnt, f32);
      acc += __shfl_xor(acc,1,64); acc += __shfl_xor(acc,2,64); acc += __shfl_xor(acc,4,64);
      if (q==0) wcl[g*8+nl] = acc;
    }
    __syncthreads();
    if (tid < 8){
      int n = nbase + tid;
      float h0v = h0_lds[n];
      float z2 = sigm(u2l[tid]   + gld(Uhz2_b, n, f32) + wcl[tid]);
      float r2 = sigm(u2l[8+tid] + gld(Uhr2_b, n, f32) + wcl[8+tid]);
      float hc = tanh_c((u2l[16+tid] + gld(Uhh2_b, n, f32))*r2 + wcl[16+tid]);
      float h2v = z2*h0v + (1.f - z2)*hc;
      h2v = lm*h2v + (1.f - lm)*h0v;
      astore(&h_ws[b*256 + n], h2v);
      out[OFF_H2 + (t*8+b)*256 + n] = h2v;
    }
    bar_t += 32; group_bar(ctr, bar_t);   // B4: h2 complete
  }
}

// ---------------- host ----------------

extern "C" void kernel_launch(void* const* d_in, const int* in_sizes, int n_in,
                              void* d_out, int out_size, void* d_ws, size_t ws_size,
                              hipStream_t stream){
  (void)in_sizes; (void)n_in; (void)out_size;
  if (ws_size < WS_NEED) return;

  const void* remb       = d_in[0];
  const void* re_emb     = d_in[1];
  const void* ly_mask    = d_in[2];
  const void* context    = d_in[3];
  const void* cmask      = d_in[4];
  const void* init_state = d_in[5];
  const void* Wyz_w = d_in[6];  const void* Wyz_b = d_in[7];
  const void* Wyr_w = d_in[8];  const void* Wyr_b = d_in[9];
  const void* Wyh_w = d_in[10]; const void* Wyh_b = d_in[11];
  const void* Uhz0  = d_in[12];
  const void* Uhr0  = d_in[13];
  const void* Uhh0  = d_in[14];
  const void* UaC_w = d_in[15]; const void* UaC_b = d_in[16];
  const void* WaC_w = d_in[17];
  const void* QC_w  = d_in[18];
  const void* UfC_w = d_in[19]; const void* UfC_b = d_in[20];
  const void* vaC_w = d_in[21]; const void* vaC_b = d_in[22];
  const void* Uhz2  = d_in[23]; const void* Uhz2_b = d_in[24];
  const void* Uhr2  = d_in[25]; const void* Uhr2_b = d_in[26];
  const void* Uhh2  = d_in[27]; const void* Uhh2_b = d_in[28];
  const void* Wcz   = d_in[29];
  const void* Wcr   = d_in[30];
  const void* Wch   = d_in[31];
  const int*  rp    = (const int*)d_in[32];

  char* ws = (char*)d_ws;
  float* sbp   = (float*)(ws + OFF_SB);
  float* UaCT  = (float*)(ws + OFF_TRAN);
  float* buf   = (float*)(ws + OFF_BUF);
  float* pctx  = (float*)(ws + OFF_PCTX);
  float* FKt   = (float*)(ws + OFF_FKT);
  float* rawp  = (float*)(ws + OFF_RAWP);
  float* h_ws  = (float*)(ws + OFF_H);
  float* h0_ws = (float*)(ws + OFF_H0);
  u32*   syncg = (u32*)  (ws + OFF_SYNC);
  int*   flag  = (int*)  (ws + OFF_FLG);
  float* out   = (float*)d_out;

  k_detect<<<1, 256, 0, stream>>>((const u16*)context, flag);
  k_pre1 <<<120, 256, 0, stream>>>(UaC_w, UaCT, QC_w, UfC_w, FKt, flag);
  k_pctx2<<<144, 256, 0, stream>>>(context, UaCT, UaC_b, UfC_b, pctx, flag);
  // region0 reuse: UaCT dead after k_pctx2 -> sb/buf may now overwrite it
  k_pre2 <<<1024, 256, 0, stream>>>(remb, re_emb, Wyz_w, Wyz_b, Wyr_w, Wyr_b, Wyh_w, Wyh_b, sbp,
                                    buf, syncg, h_ws, init_state, flag);
  k_main <<<256, 256, 0, stream>>>(ly_mask, context, cmask,
                                   Uhz0, Uhr0, Uhh0, WaC_w, vaC_w, vaC_b,
                                   Uhz2, Uhz2_b, Uhr2, Uhr2_b, Uhh2, Uhh2_b,
                                   Wcz, Wcr, Wch, rp,
                                   pctx, sbp, FKt,
                                   buf, h_ws, h0_ws, rawp, syncg, out, flag);
}

// Round 17
// 1028.337 us; speedup vs baseline: 2.4186x; 1.0489x over previous
//
#include <hip/hip_runtime.h>
#include <stdint.h>

typedef unsigned short u16;
typedef unsigned int   u32;

// problem dims
#define TB_ 8      // batch
#define NN_ 256    // state n
#define DD_ 684    // context depth d
#define PP_ 576    // H*W = 12*48

// workspace layout (bytes). Region0 [0, 1486848) time-shared BY LAUNCH ORDER:
//   phase1: UaCT (f32 [684][512]) @0        -- k_pre1 writes, k_pctx2 reads
//   phase2: sb @0 + buf @786432             -- k_pre2 writes AFTER k_pctx2 consumed UaCT
#define OFF_SB    0u
#define OFF_TRAN  0u
#define OFF_BUF   786432u
#define OFF_PCTX  1486848u    // f32 [b][p(576)][a(512)]
#define OFF_FKT   10924032u   // f32 [tap(9)][a(512)]
#define OFF_RAWP  10942464u   // f32 [b][ja(16)][p(576)]; row ja written by 2 blocks (p-halves)
#define OFF_H     11237376u   // f32 [b][n]
#define OFF_H0    11245568u   // f32 [b][n]
#define OFF_EAL   11253760u   // (unused this rev)
#define OFF_SYNC  11272192u   // u32 [b][128]: [0]=barrier ctr
#define OFF_FLG   11276288u   // int dtype flag
#define WS_NEED   11276304u

// output offsets (elements, f32)
#define OFF_H2   0
#define OFF_CTC  65536
#define OFF_CTP  240640
#define OFF_AL   415744
#define OFF_APO  563200

__device__ __forceinline__ float b2f(u16 v){ union{u32 i; float f;} x; x.i = ((u32)v)<<16; return x.f; }
__device__ __forceinline__ float gld(const void* p, size_t i, int f32){
  if (f32) return ((const float*)p)[i];
  return b2f(((const u16*)p)[i]);
}
__device__ __forceinline__ float bl(u32 v){ union{u32 i; float f;} x; x.i = v<<16; return x.f; }
__device__ __forceinline__ float bh(u32 v){ union{u32 i; float f;} x; x.i = v & 0xFFFF0000u; return x.f; }

// coherence-point (L3) scalar access for cross-block data.
__device__ __forceinline__ float aload(const float* p){
  u32 v = __hip_atomic_load((const u32*)p, __ATOMIC_RELAXED, __HIP_MEMORY_SCOPE_AGENT);
  union{u32 i; float f;} x; x.i = v; return x.f;
}
__device__ __forceinline__ void astore(float* p, float v){
  union{float f; u32 i;} x; x.f = v;
  __hip_atomic_store((u32*)p, x.i, __ATOMIC_RELAXED, __HIP_MEMORY_SCOPE_AGENT);
}

// coherent wide load (one 16B line piece, waits internally; consumers depend on
// the output reg so ordering is safe).
__device__ __forceinline__ float4 cload4(const float* p){
  float4 v;
  asm volatile("global_load_dwordx4 %0, %1, off sc0 sc1\n\ts_waitcnt vmcnt(0)"
               : "=v"(v) : "v"(p) : "memory");
  return v;
}

__device__ __forceinline__ float rcpf(float x){ return __builtin_amdgcn_rcpf(x); }
__device__ __forceinline__ float sigm(float x){
  x = fminf(fmaxf(x, -30.f), 30.f);
  return rcpf(1.f + __expf(-x));
}
__device__ __forceinline__ float tanh_c(float x){
  x = fminf(fmaxf(x, -15.f), 15.f);
  float e = __expf(2.f*x);
  return 1.f - 2.f*rcpf(e + 1.f);
}

__device__ __forceinline__ float dot8(uint4 u, const float* s){
  float a = fmaf(bl(u.x), s[0], bh(u.x)*s[1]);
  a = fmaf(bl(u.y), s[2], a); a = fmaf(bh(u.y), s[3], a);
  a = fmaf(bl(u.z), s[4], a); a = fmaf(bh(u.z), s[5], a);
  a = fmaf(bl(u.w), s[6], a); a = fmaf(bh(u.w), s[7], a);
  return a;
}
__device__ __forceinline__ float dot4t(uint2 u, const float* s, float a){
  a = fmaf(bl(u.x), s[0], a); a = fmaf(bh(u.x), s[1], a);
  a = fmaf(bl(u.y), s[2], a); a = fmaf(bh(u.y), s[3], a);
  return a;
}
__device__ __forceinline__ float dotf(const float* w, const float* s, int n){
  float a = 0.f;
  #pragma unroll 4
  for (int k=0;k<n;k+=4){
    float4 u = *(const float4*)(w+k);
    a = fmaf(u.x, s[k], a);   a = fmaf(u.y, s[k+1], a);
    a = fmaf(u.z, s[k+2], a); a = fmaf(u.w, s[k+3], a);
  }
  return a;
}
// n must be a multiple of 4
__device__ __forceinline__ float dotw(const void* W, size_t row_off, const float* s, int n, int f32){
  if (f32) return dotf((const float*)W + row_off, s, n);
  const u16* r = (const u16*)W + row_off;
  float a = 0.f;
  int k = 0;
  for (; k+8 <= n; k += 8) a += dot8(*(const uint4*)(r+k), s+k);
  if (k < n) a = dot4t(*(const uint2*)(r+k), s+k, a);
  return a;
}

// counter barrier (R1 primitive, zero outliers): __syncthreads drains all waves'
// vmem (compiler emits vmcnt(0) before s_barrier); tid0 RMW + throttled poll.
__device__ __forceinline__ void group_bar(u32* ctr, u32 target){
  __syncthreads();
  if (threadIdx.x == 0){
    __hip_atomic_fetch_add(ctr, 1u, __ATOMIC_RELAXED, __HIP_MEMORY_SCOPE_AGENT);
    while (__hip_atomic_load(ctr, __ATOMIC_RELAXED, __HIP_MEMORY_SCOPE_AGENT) < target)
      __builtin_amdgcn_s_sleep(2);
  }
  __syncthreads();
}

// ---------------- dtype detector ----------------
__global__ void k_detect(const u16* __restrict__ ctx_u16, int* __restrict__ flag){
  __shared__ int cnt;
  if (threadIdx.x == 0) cnt = 0;
  __syncthreads();
  int bad = 0;
  for (int k = threadIdx.x; k < 512; k += 256){
    u16 v = ctx_u16[k];
    int e = (v >> 7) & 0xFF;
    bool sane = (v == 0u) || (v == 0x8000u) || (e >= 102 && e <= 141);
    if (!sane) bad++;
  }
  atomicAdd(&cnt, bad);
  __syncthreads();
  if (threadIdx.x == 0) flag[0] = (cnt > 64) ? 1 : 0;
}

// ---------------- pre1: tran(88) + fk(32) = 120 blocks (runs BEFORE k_pctx2)
__global__ __launch_bounds__(256) void k_pre1(
    const void* __restrict__ UaC_w, float* __restrict__ UaCT,
    const void* __restrict__ QC, const void* __restrict__ UfC, float* __restrict__ FKt,
    const int* __restrict__ flag)
{
  const int f32 = flag[0];
  const int tid = threadIdx.x;
  __shared__ float smem[4608];
  int bid = blockIdx.x;

  if (bid < 88){
    int ab = bid / 11, db = bid - ab*11;
    int tc = tid & 63, tr = tid >> 6;
    int d0 = db*64, a0 = ab*64;
    for (int rr = tr; rr < 64; rr += 4){
      int d = d0 + tc;
      if (d < DD_) smem[rr*65 + tc] = gld(UaC_w, (size_t)(a0+rr)*DD_ + d, f32);
    }
    __syncthreads();
    for (int rr = tr; rr < 64; rr += 4){
      int d = d0 + rr;
      if (d < DD_) UaCT[(size_t)d*512 + a0 + tc] = smem[tc*65 + rr];
    }
    return;
  }
  bid -= 88;
  {
    for (int k=tid;k<4608;k+=256) smem[k] = gld(QC, k, f32);
    __syncthreads();
    const int lane = tid & 63;
    const int wid = bid*4 + (tid>>6);
    for (int rr=0; rr<4; rr++){
      const int a = wid*4 + rr;
      float acc[9];
      #pragma unroll
      for (int tt=0;tt<9;tt++) acc[tt]=0.f;
      #pragma unroll
      for (int k=0;k<8;k++){
        int c = lane + k*64;
        float v = gld(UfC, (size_t)a*512 + c, f32);
        const float* q = &smem[c*9];
        #pragma unroll
        for (int tt=0;tt<9;tt++) acc[tt] = fmaf(v, q[tt], acc[tt]);
      }
      #pragma unroll
      for (int off=1; off<64; off<<=1){
        #pragma unroll
        for (int tt=0;tt<9;tt++) acc[tt] += __shfl_xor(acc[tt], off, 64);
      }
      #pragma unroll
      for (int tt=0;tt<9;tt++) if (lane == tt) FKt[tt*512 + a] = acc[tt];
    }
  }
}

// pctx[b][p][a] = context[b,:,p].UaC[a,:] + UaC_b[a] + UfC_b[a]
// 288 blocks (16-p tiles): LDS 43.8 KB -> 2 blocks/CU, all CUs busy
// (R16 ran 144 blocks x 87.6 KB = 1 block/CU on 56% of CUs).
__global__ __launch_bounds__(256) void k_pctx2(const void* __restrict__ context,
    const float* __restrict__ UaCT, const void* __restrict__ UaC_b, const void* __restrict__ UfC_b,
    float* __restrict__ pctx, const int* __restrict__ flag){
  const int f32 = flag[0];
  const int blk = blockIdx.x;
  const int b = blk / 36;
  const int pbase = (blk - b*36) * 16;
  __shared__ float ctx[16][DD_];
  const int tid = threadIdx.x;
  for (int k=tid; k<16*DD_; k+=256){
    int p = k & 15, d = k >> 4;
    ctx[p][d] = gld(context, ((size_t)(b*DD_+d))*PP_ + pbase + p, f32);
  }
  __syncthreads();
  const int a0 = (tid & 127) * 4;
  const int pr = (tid >> 7) * 8;
  float acc[8][4];
  #pragma unroll
  for (int p=0;p<8;p++){ acc[p][0]=0.f; acc[p][1]=0.f; acc[p][2]=0.f; acc[p][3]=0.f; }
  for (int d=0; d<DD_; d+=4){
    float4 w0 = *(const float4*)&UaCT[(size_t)(d+0)*512 + a0];
    float4 w1 = *(const float4*)&UaCT[(size_t)(d+1)*512 + a0];
    float4 w2 = *(const float4*)&UaCT[(size_t)(d+2)*512 + a0];
    float4 w3 = *(const float4*)&UaCT[(size_t)(d+3)*512 + a0];
    #pragma unroll
    for (int p=0;p<8;p++){
      float4 c = *(const float4*)(&ctx[pr+p][d]);
      acc[p][0] = fmaf(c.x, w0.x, acc[p][0]); acc[p][1] = fmaf(c.x, w0.y, acc[p][1]);
      acc[p][2] = fmaf(c.x, w0.z, acc[p][2]); acc[p][3] = fmaf(c.x, w0.w, acc[p][3]);
      acc[p][0] = fmaf(c.y, w1.x, acc[p][0]); acc[p][1] = fmaf(c.y, w1.y, acc[p][1]);
      acc[p][2] = fmaf(c.y, w1.z, acc[p][2]); acc[p][3] = fmaf(c.y, w1.w, acc[p][3]);
      acc[p][0] = fmaf(c.z, w2.x, acc[p][0]); acc[p][1] = fmaf(c.z, w2.y, acc[p][1]);
      acc[p][2] = fmaf(c.z, w2.z, acc[p][2]); acc[p][3] = fmaf(c.z, w2.w, acc[p][3]);
      acc[p][0] = fmaf(c.w, w3.x, acc[p][0]); acc[p][1] = fmaf(c.w, w3.y, acc[p][1]);
      acc[p][2] = fmaf(c.w, w3.z, acc[p][2]); acc[p][3] = fmaf(c.w, w3.w, acc[p][3]);
    }
  }
  float b0 = gld(UaC_b, a0+0, f32) + gld(UfC_b, a0+0, f32);
  float b1 = gld(UaC_b, a0+1, f32) + gld(UfC_b, a0+1, f32);
  float b2 = gld(UaC_b, a0+2, f32) + gld(UfC_b, a0+2, f32);
  float b3 = gld(UaC_b, a0+3, f32) + gld(UfC_b, a0+3, f32);
  #pragma unroll
  for (int p=0;p<8;p++){
    float4 v; v.x = acc[p][0]+b0; v.y = acc[p][1]+b1; v.z = acc[p][2]+b2; v.w = acc[p][3]+b3;
    *(float4*)&pctx[((size_t)(b*PP_ + pbase + pr + p))*512 + a0] = v;
  }
}

// ---------------- pre2: sb(768) + init(256) = 1024 blocks (AFTER k_pctx2)
__global__ __launch_bounds__(256) void k_pre2(
    const void* __restrict__ remb, const void* __restrict__ re_emb,
    const void* __restrict__ Wz, const void* __restrict__ bz,
    const void* __restrict__ Wr, const void* __restrict__ br,
    const void* __restrict__ Wh, const void* __restrict__ bhh,
    float* __restrict__ sb,
    float* __restrict__ buf, u32* __restrict__ sync, float* __restrict__ h,
    const void* __restrict__ init_state,
    const int* __restrict__ flag)
{
  const int f32 = flag[0];
  const int tid = threadIdx.x;
  int bid = blockIdx.x;
  if (bid < 768){
    __shared__ float emb[512];
    int g = bid >> 8;
    int tb = bid & 255; int t = tb >> 3; int b = tb & 7;
    emb[tid]     = gld(remb,   (size_t)(t*8+b)*256 + tid, f32);
    emb[tid+256] = gld(re_emb, (size_t)(t*8+b)*256 + tid, f32);
    __syncthreads();
    const void* W = (g==0?Wz:(g==1?Wr:Wh));
    const void* bias = (g==0?bz:(g==1?br:bhh));
    float acc = gld(bias, tid, f32) + dotw(W, (size_t)tid*512, emb, 512, f32);
    sb[(((size_t)g*32+t)*8+b)*256 + tid] = acc;
    return;
  }
  bid -= 768;
  {
    int i = bid*256 + tid;
    int stride = 256*256;
    for (int k=i; k<32*TB_*DD_; k+=stride) buf[k] = 0.f;
    for (int k=i; k<TB_*128;    k+=stride) sync[k] = 0u;
    for (int k=i; k<TB_*NN_;    k+=stride) h[k]   = gld(init_state, k, f32);
  }
}

// ---------------- persistent main: 256 blocks = 8 groups(b) x 32 (j); 256 threads
// FOUR barriers/step: B1 h0, B2 rawp, B3 ctC, B4 h2 (R16 structure).
// This rev: broadcast gathers (hprev, h0, ctC) use wide coherent dwordx4 loads
// (4x fewer L3 transactions than scalar aloads).

__global__ __launch_bounds__(256, 1) void k_main(
    const void* __restrict__ ly_mask, const void* __restrict__ context, const void* __restrict__ cmask,
    const void* __restrict__ Uhz0, const void* __restrict__ Uhr0, const void* __restrict__ Uhh0,
    const void* __restrict__ WaC, const void* __restrict__ vaC_w, const void* __restrict__ vaC_b,
    const void* __restrict__ Uhz2, const void* __restrict__ Uhz2_b,
    const void* __restrict__ Uhr2, const void* __restrict__ Uhr2_b,
    const void* __restrict__ Uhh2, const void* __restrict__ Uhh2_b,
    const void* __restrict__ Wcz, const void* __restrict__ Wcr, const void* __restrict__ Wch,
    const int* __restrict__ rp,
    const float* __restrict__ pctx, const float* __restrict__ sb, const float* __restrict__ FKt,
    float* buf, float* h_ws, float* h0_ws, float* rawp, u32* syncg,
    float* out, const int* __restrict__ flag)
{
  const int f32 = flag[0];
  const int tid = threadIdx.x;
  const int b = blockIdx.x >> 5;
  const int j = blockIdx.x & 31;
  const int ja = j >> 1, jp = j & 1;
  const int abase = ja*32;                    // 32-a slice for scores/query
  const int pbase = jp*288;                   // 288-p half for scores
  const int nbase = j*8;                      // 8-n slice for GRU gates
  const int dbase = j*21 + (j < 12 ? j : 12); // 22,22,..(x12),21,...(x20)
  const int dcnt  = (j < 12) ? 22 : 21;
  const int pown  = j*18;                     // 18-p AL/APO owner window

  __shared__ float hprev[NN_], h0_lds[NN_];
  __shared__ float ap_lds[PP_], al_lds[PP_], cm_lds[PP_];
  __shared__ float ctc_lds[DD_];
  __shared__ float fk_lds[9*32], vac_lds[32], q_lds[32], qpart[256];
  __shared__ float g1[24], u2l[24], wcl[24];
  __shared__ float red[4];
  __shared__ float sp[16*PP_];                // staged rawp [j2][p] (36.9 KB)

  for (int k=tid; k<288; k+=256) fk_lds[k] = FKt[(k>>5)*512 + abase + (k&31)];
  if (tid < 32) vac_lds[tid] = gld(vaC_w, abase + tid, f32);
  cm_lds[tid]     = gld(cmask, b*PP_ + tid, f32);
  cm_lds[tid+256] = gld(cmask, b*PP_ + tid + 256, f32);
  if (tid < 64) cm_lds[tid+512] = gld(cmask, b*PP_ + tid + 512, f32);
  ap_lds[tid] = 0.f; ap_lds[tid+256] = 0.f;
  if (tid < 64) ap_lds[tid+512] = 0.f;
  const float vb = gld(vaC_b, 0, f32);

  u32* ctr = syncg + b*128;
  u32 bar_t = 0;
  const int p0 = tid, p1 = tid + 256, p2 = tid + 512;
  const bool has3 = (tid < 64);

  for (int t=0; t<32; t++){
    const float lm = gld(ly_mask, t*8+b, f32);

    //---- P1: stage h2(t-1) wide; GRU1 n-slice (8 n, 8-lane dots); ctP owner chunk
    if (tid < 64) *(float4*)&hprev[tid*4] = cload4(&h_ws[b*256 + tid*4]);
    __syncthreads();
    if (tid < 192){
      int item = tid >> 3, q = tid & 7;        // 24 dots (3g x 8n), 8 lanes x 32 elems
      int g = item >> 3, nl = item & 7;
      int n = nbase + nl;
      const void* U = (g==0 ? Uhz0 : (g==1 ? Uhr0 : Uhh0));
      float acc = dotw(U, (size_t)n*256 + q*32, &hprev[q*32], 32, f32);
      acc += __shfl_xor(acc,1,64); acc += __shfl_xor(acc,2,64); acc += __shfl_xor(acc,4,64);
      if (q==0) g1[g*8+nl] = acc;
    }
    __syncthreads();
    if (tid < 8){
      int n = nbase + tid;
      float hp = hprev[n];
      float z0 = sigm(g1[tid]    + sb[(((size_t)t)*8+b)*256 + n]);
      float r0 = sigm(g1[8+tid]  + sb[(((size_t)(32+t))*8+b)*256 + n]);
      float hc = tanh_c(g1[16+tid]*r0 + sb[(((size_t)(64+t))*8+b)*256 + n]);
      float h0v = z0*hp + (1.f - z0)*hc;
      h0v = lm*h0v + (1.f - lm)*hp;
      astore(&h0_ws[b*256 + n], h0v);
    }
    {
      int rpos = rp[t*8+b];
      if ((unsigned)rpos > 31u) rpos = 31;
      if (tid < dcnt){
        int d = dbase + tid;
        out[OFF_CTP + (t*8+b)*DD_ + d] = aload(&buf[((size_t)rpos*8+b)*DD_ + d]);
      }
    }
    bar_t += 32; group_bar(ctr, bar_t);   // B1: h0 complete

    //---- P2: stage h0 wide; query (32 a) + scores (288 p x 32 a) + U2 dots
    if (tid < 64) *(float4*)&h0_lds[tid*4] = cload4(&h0_ws[b*256 + tid*4]);
    __syncthreads();
    {
      int ai = tid & 31, nb = tid >> 5;        // 8 x 32
      qpart[nb*32 + ai] = dotw(WaC, (size_t)(abase+ai)*256 + nb*32, &h0_lds[nb*32], 32, f32);
    }
    __syncthreads();
    if (tid < 32){
      float qv = 0.f;
      #pragma unroll
      for (int nb2=0;nb2<8;nb2++) qv += qpart[nb2*32 + tid];
      q_lds[tid] = qv;
    }
    __syncthreads();
    #pragma unroll 1
    for (int round=0; round<2; round++){
      int item = tid + round*256;              // 288 items = 288 p
      if (item >= 288) break;
      int p = pbase + item;
      float PQ[32];
      const float* pc = pctx + ((size_t)(b*PP_ + p))*512 + abase;
      #pragma unroll
      for (int q8=0;q8<8;q8++){
        float4 u = *(const float4*)(pc + q8*4);
        PQ[q8*4+0]=u.x; PQ[q8*4+1]=u.y; PQ[q8*4+2]=u.z; PQ[q8*4+3]=u.w;
      }
      int hh_ = p / 48, ww_ = p - hh_*48;
      #pragma unroll
      for (int kh=0;kh<3;kh++){
        int h2_ = hh_ + kh - 1;
        if ((unsigned)h2_ >= 12u) continue;
        #pragma unroll
        for (int kw=0;kw<3;kw++){
          int w2_ = ww_ + kw - 1;
          if ((unsigned)w2_ >= 48u) continue;
          float av = ap_lds[h2_*48 + w2_];
          const float* fkp = &fk_lds[(kh*3+kw)*32];
          #pragma unroll
          for (int ai=0;ai<32;ai++) PQ[ai] = fmaf(av, fkp[ai], PQ[ai]);
        }
      }
      float racc = 0.f;
      #pragma unroll
      for (int ai=0;ai<32;ai++)
        racc = fmaf(vac_lds[ai], tanh_c(PQ[ai] + q_lds[ai]), racc);
      astore(&rawp[((size_t)(b*16 + ja))*PP_ + p], racc);
    }
    if (tid < 192){
      int item = tid >> 3, q = tid & 7;
      int g = item >> 3, nl = item & 7;
      int n = nbase + nl;
      const void* U = (g==0 ? Uhz2 : (g==1 ? Uhr2 : Uhh2));
      float acc = dotw(U, (size_t)n*256 + q*32, &h0_lds[q*32], 32, f32);
      acc += __shfl_xor(acc,1,64); acc += __shfl_xor(acc,2,64); acc += __shfl_xor(acc,4,64);
      if (q==0) u2l[g*8+nl] = acc;
    }
    bar_t += 32; group_bar(ctr, bar_t);   // B2: rawp complete

    //---- P3: wide coherent gather of all 16 rawp rows -> LDS; replicated
    //         e/S/alpha/ap (identical op order in every block); owner AL/APO;
    //         ctC owner d-chunk
    {
      const float* base = rawp + (size_t)b*16*PP_ + tid*4;
      float4 rv[9];
      #pragma unroll
      for (int k=0;k<9;k++){
        asm volatile("global_load_dwordx4 %0, %1, off sc0 sc1"
                     : "=&v"(rv[k]) : "v"(base + k*1024) : "memory");
      }
      asm volatile("s_waitcnt vmcnt(0)" ::: "memory");
      __builtin_amdgcn_sched_barrier(0);
      #pragma unroll
      for (int k=0;k<9;k++) *(float4*)&sp[tid*4 + k*1024] = rv[k];
    }
    __syncthreads();
    {
      float psum = 0.f;
      #pragma unroll 1
      for (int rep=0; rep<3; rep++){
        int p = tid + rep*256;
        if (p >= PP_) break;
        float raw = vb;
        #pragma unroll
        for (int j2=0;j2<16;j2++) raw += sp[j2*PP_ + p];
        raw = fminf(fmaxf(raw, -60.f), 60.f);
        float e = __expf(raw) * cm_lds[p];
        al_lds[p] = e; psum += e;
      }
      #pragma unroll
      for (int off=1; off<64; off<<=1) psum += __shfl_xor(psum, off, 64);
      if ((tid & 63)==0) red[tid>>6] = psum;
    }
    __syncthreads();
    {
      float S = red[0] + red[1] + red[2] + red[3];
      S = fmaxf(S, 1e-30f);
      float inv = rcpf(S);
      float a0 = al_lds[p0]*inv + 1e-10f; al_lds[p0] = a0; ap_lds[p0] += a0;
      float a1 = al_lds[p1]*inv + 1e-10f; al_lds[p1] = a1; ap_lds[p1] += a1;
      if (has3){ float a2 = al_lds[p2]*inv + 1e-10f; al_lds[p2] = a2; ap_lds[p2] += a2; }
    }
    __syncthreads();
    if (tid < 18){
      int p = pown + tid;
      out[OFF_AL  + (t*8+b)*PP_ + p] = al_lds[p];
      out[OFF_APO + (t*8+b)*PP_ + p] = ap_lds[p];
    }
    {
      int dd = tid >> 2, q = tid & 3;
      if (dd < dcnt){
        int d = dbase + dd;
        float acc;
        if (f32) acc = dotf((const float*)context + ((size_t)(b*DD_+d))*PP_ + q*144, &al_lds[q*144], 144);
        else {
          const u16* crow = (const u16*)context + ((size_t)(b*DD_+d))*PP_ + q*144;
          acc = 0.f;
          #pragma unroll 6
          for (int k=0;k<144;k+=8) acc += dot8(*(const uint4*)(crow+k), &al_lds[q*144+k]);
        }
        acc += __shfl_xor(acc,1,64); acc += __shfl_xor(acc,2,64);
        if (q==0){
          astore(&out[OFF_CTC + (t*8+b)*DD_ + d], acc);
          if (t < 31) astore(&buf[(((size_t)(t+1))*8+b)*DD_ + d], acc);  // row 32 never read
        }
      }
    }
    bar_t += 32; group_bar(ctr, bar_t);   // B3: ctC complete

    //---- P4: ctC wide broadcast, Wc dots (8-lane chunks 88.. + 68), h2 combine
    if (tid < 171) *(float4*)&ctc_lds[tid*4] = cload4(&out[OFF_CTC + (t*8+b)*DD_ + tid*4]);
    __syncthreads();
    if (tid < 192){
      int item = tid >> 3, q = tid & 7;        // 24 dots (3g x 8n), 8 lanes
      int g = item >> 3, nl = item & 7;
      int n = nbase + nl;
      const void* W = (g==0 ? Wcz : (g==1 ? Wcr : Wch));
      int base = q*88, cnt = (q==7) ? 68 : 88;
      float acc = dotw(W, (size_t)n*DD_ + base, &ctc_lds[base], cnt, f32);
      acc += __shfl_xor(acc,1,64); acc += __shfl_xor(acc,2,64); acc += __shfl_xor(acc,4,64);
      if (q==0) wcl[g*8+nl] = acc;
    }
    __syncthreads();
    if (tid < 8){
      int n = nbase + tid;
      float h0v = h0_lds[n];
      float z2 = sigm(u2l[tid]   + gld(Uhz2_b, n, f32) + wcl[tid]);
      float r2 = sigm(u2l[8+tid] + gld(Uhr2_b, n, f32) + wcl[8+tid]);
      float hc = tanh_c((u2l[16+tid] + gld(Uhh2_b, n, f32))*r2 + wcl[16+tid]);
      float h2v = z2*h0v + (1.f - z2)*hc;
      h2v = lm*h2v + (1.f - lm)*h0v;
      astore(&h_ws[b*256 + n], h2v);
      out[OFF_H2 + (t*8+b)*256 + n] = h2v;
    }
    bar_t += 32; group_bar(ctr, bar_t);   // B4: h2 complete
  }
}

// ---------------- host ----------------

extern "C" void kernel_launch(void* const* d_in, const int* in_sizes, int n_in,
                              void* d_out, int out_size, void* d_ws, size_t ws_size,
                              hipStream_t stream){
  (void)in_sizes; (void)n_in; (void)out_size;
  if (ws_size < WS_NEED) return;

  const void* remb       = d_in[0];
  const void* re_emb     = d_in[1];
  const void* ly_mask    = d_in[2];
  const void* context    = d_in[3];
  const void* cmask      = d_in[4];
  const void* init_state = d_in[5];
  const void* Wyz_w = d_in[6];  const void* Wyz_b = d_in[7];
  const void* Wyr_w = d_in[8];  const void* Wyr_b = d_in[9];
  const void* Wyh_w = d_in[10]; const void* Wyh_b = d_in[11];
  const void* Uhz0  = d_in[12];
  const void* Uhr0  = d_in[13];
  const void* Uhh0  = d_in[14];
  const void* UaC_w = d_in[15]; const void* UaC_b = d_in[16];
  const void* WaC_w = d_in[17];
  const void* QC_w  = d_in[18];
  const void* UfC_w = d_in[19]; const void* UfC_b = d_in[20];
  const void* vaC_w = d_in[21]; const void* vaC_b = d_in[22];
  const void* Uhz2  = d_in[23]; const void* Uhz2_b = d_in[24];
  const void* Uhr2  = d_in[25]; const void* Uhr2_b = d_in[26];
  const void* Uhh2  = d_in[27]; const void* Uhh2_b = d_in[28];
  const void* Wcz   = d_in[29];
  const void* Wcr   = d_in[30];
  const void* Wch   = d_in[31];
  const int*  rp    = (const int*)d_in[32];

  char* ws = (char*)d_ws;
  float* sbp   = (float*)(ws + OFF_SB);
  float* UaCT  = (float*)(ws + OFF_TRAN);
  float* buf   = (float*)(ws + OFF_BUF);
  float* pctx  = (float*)(ws + OFF_PCTX);
  float* FKt   = (float*)(ws + OFF_FKT);
  float* rawp  = (float*)(ws + OFF_RAWP);
  float* h_ws  = (float*)(ws + OFF_H);
  float* h0_ws = (float*)(ws + OFF_H0);
  u32*   syncg = (u32*)  (ws + OFF_SYNC);
  int*   flag  = (int*)  (ws + OFF_FLG);
  float* out   = (float*)d_out;

  k_detect<<<1, 256, 0, stream>>>((const u16*)context, flag);
  k_pre1 <<<120, 256, 0, stream>>>(UaC_w, UaCT, QC_w, UfC_w, FKt, flag);
  k_pctx2<<<288, 256, 0, stream>>>(context, UaCT, UaC_b, UfC_b, pctx, flag);
  // region0 reuse: UaCT dead after k_pctx2 -> sb/buf may now overwrite it
  k_pre2 <<<1024, 256, 0, stream>>>(remb, re_emb, Wyz_w, Wyz_b, Wyr_w, Wyr_b, Wyh_w, Wyh_b, sbp,
                                    buf, syncg, h_ws, init_state, flag);
  k_main <<<256, 256, 0, stream>>>(ly_mask, context, cmask,
                                   Uhz0, Uhr0, Uhh0, WaC_w, vaC_w, vaC_b,
                                   Uhz2, Uhz2_b, Uhr2, Uhr2_b, Uhh2, Uhh2_b,
                                   Wcz, Wcr, Wch, rp,
                                   pctx, sbp, FKt,
                                   buf, h_ws, h0_ws, rawp, syncg, out, flag);
}